// Round 19
// baseline (104.504 us; speedup 1.0000x reference)
//
#include <hip/hip_runtime.h>
#include <cmath>

#define NB 64
#define NCC 256
#define NH 36
#define NW 36
#define NHW 1296
#define NK 16
#define NI 8
#define SC (1.0f/16.0f)
#define LOG2E 1.4426950408889634f
#define NPAD 1312   // 41*32

typedef __attribute__((ext_vector_type(16))) float f32x16;
typedef __attribute__((ext_vector_type(4)))  float f32x4;
typedef __attribute__((ext_vector_type(4)))  short s16x4;
typedef __attribute__((ext_vector_type(8)))  unsigned short u16x8;
typedef __attribute__((ext_vector_type(2)))  unsigned int u32x2;

__device__ __forceinline__ float hatc(float t){
  t = fminf(fmaxf(t, -1.0f), 1.0f);
  float a = 1.0f + t, bq = 1.0f - t;
  return (t < 0.0f) ? 0.5f*a*a : 1.0f - 0.5f*bq*bq;
}

__device__ __forceinline__ unsigned short bf16rn(float f){
  unsigned int u = __builtin_bit_cast(unsigned int, f);
  return (unsigned short)((u + 0x7FFFu + ((u >> 16) & 1u)) >> 16);
}
__device__ __forceinline__ float bf16tof(unsigned short h){
  unsigned int u = ((unsigned int)h) << 16;
  return __builtin_bit_cast(float, u);
}

// ---- K1: PrRoI pooling; separable: colsum over rows, then wx finish -----
__global__ __launch_bounds__(256) void k_prpool(const float* __restrict__ feat1,
    const float* __restrict__ bb1, float* __restrict__ kflat){
  int blk = blockIdx.x;          // b*64 + cg
  int b = blk >> 6, cg = blk & 63;
  int t = threadIdx.x, w = t >> 6, lane = t & 63;
  int c = cg*4 + w;
  __shared__ float4 wY4[36];
  __shared__ float  wXp[36*5];
  __shared__ float  sfeat[4][1296];
  float bx = bb1[b*4+0], by = bb1[b*4+1], bwv = bb1[b*4+2], bhv = bb1[b*4+3];
  float x1 = bx*SC, y1 = by*SC;
  float binw = bwv*SC*0.25f, binh = bhv*SC*0.25f;
  if (t < 36){
    float fi = (float)t;
    float4 r;
    r.x = hatc(y1 + 1.0f*binh - fi) - hatc(y1 + 0.0f*binh - fi);
    r.y = hatc(y1 + 2.0f*binh - fi) - hatc(y1 + 1.0f*binh - fi);
    r.z = hatc(y1 + 3.0f*binh - fi) - hatc(y1 + 2.0f*binh - fi);
    r.w = hatc(y1 + 4.0f*binh - fi) - hatc(y1 + 3.0f*binh - fi);
    wY4[t] = r;
  } else if (t < 72){
    int i = t - 36;
    float fi = (float)i;
    wXp[i*5+0] = hatc(x1 + 1.0f*binw - fi) - hatc(x1 + 0.0f*binw - fi);
    wXp[i*5+1] = hatc(x1 + 2.0f*binw - fi) - hatc(x1 + 1.0f*binw - fi);
    wXp[i*5+2] = hatc(x1 + 3.0f*binw - fi) - hatc(x1 + 2.0f*binw - fi);
    wXp[i*5+3] = hatc(x1 + 4.0f*binw - fi) - hatc(x1 + 3.0f*binw - fi);
  }
  // stage this wave's channel into LDS (linear, coalesced)
  {
    const float4* fp4 = (const float4*)(feat1 + ((size_t)(b*256+c))*NHW);
    float4* sf4 = (float4*)sfeat[w];
    #pragma unroll
    for (int i=0;i<5;i++) sf4[i*64+lane] = fp4[i*64+lane];
    if (lane < 4) sf4[320+lane] = fp4[320+lane];
  }
  __syncthreads();

  // colsum[x][ky] = sum_h feat[h][x] * wy[h][ky]; lane = column x
  int x = (lane < 36) ? lane : 0;
  f32x4 cacc = (f32x4){0,0,0,0};
  const float* sc = sfeat[w];
  #pragma unroll 6
  for (int h2=0; h2<36; ++h2){
    float v = sc[h2*36 + x];
    float4 wy = wY4[h2];
    f32x4 wyv = {wy.x, wy.y, wy.z, wy.w};
    f32x4 vv = {v, v, v, v};
    cacc = __builtin_elementwise_fma(vv, wyv, cacc);
  }
  if (lane >= 36) cacc = (f32x4){0,0,0,0};

  // finish: accf[ky*4+kx] = wx[kx][x] * colsum[x][ky], reduce over lanes
  float wx0 = wXp[x*5+0], wx1 = wXp[x*5+1], wx2 = wXp[x*5+2], wx3 = wXp[x*5+3];
  float accf[16];
  #pragma unroll
  for (int ky=0;ky<4;ky++){
    float cy = cacc[ky];
    accf[ky*4+0] = cy*wx0;
    accf[ky*4+1] = cy*wx1;
    accf[ky*4+2] = cy*wx2;
    accf[ky*4+3] = cy*wx3;
  }
  #pragma unroll
  for (int k=0;k<16;k++){
    float a = accf[k];
    #pragma unroll
    for (int off=32; off>0; off>>=1) a += __shfl_down(a, off);
    accf[k] = a;
  }
  if (lane == 0){
    float area = binw*binh;
    float ia = (area > 0.0f) ? 1.0f/fmaxf(area,1e-12f) : 0.0f;
    float4* kp = (float4*)(kflat + ((size_t)(b*256+c))*16);
    kp[0] = make_float4(accf[0]*ia, accf[1]*ia, accf[2]*ia, accf[3]*ia);
    kp[1] = make_float4(accf[4]*ia, accf[5]*ia, accf[6]*ia, accf[7]*ia);
    kp[2] = make_float4(accf[8]*ia, accf[9]*ia, accf[10]*ia, accf[11]*ia);
    kp[3] = make_float4(accf[12]*ia, accf[13]*ia, accf[14]*ia, accf[15]*ia);
  }
}

// ---- K2: pixel corr; float4 pixel loads, 8-way channel split ------------
__global__ __launch_bounds__(512) void k_corr(const float* __restrict__ feat2,
    const float* __restrict__ kflat, float* __restrict__ corr,
    float* __restrict__ partial_se){
  int blk = blockIdx.x;          // b*6 + ch
  int b = blk / 6, ch = blk - b*6;
  int t = threadIdx.x, w = t >> 6, lane = t & 63;
  int px0 = ch*216;
  __shared__ float par[4][16][216];

  int wu = __builtin_amdgcn_readfirstlane(w);
  int c0 = wu*32;
  int l4 = (lane < 54) ? lane : 53;

  f32x4 acc[16];
  #pragma unroll
  for (int k=0;k<16;k++) acc[k] = (f32x4){0,0,0,0};

  const float* f2base = feat2 + (size_t)b*NCC*NHW + px0 + l4*4;
  const float* kfb = kflat + (size_t)b*4096;
  #pragma unroll 4
  for (int c = c0; c < c0+32; ++c){
    f32x4 r = *(const f32x4*)(f2base + (size_t)c*NHW);
    f32x16 kf = *(const f32x16*)(kfb + c*16);
    #pragma unroll
    for (int k=0;k<16;k++){
      f32x4 kv = {kf[k], kf[k], kf[k], kf[k]};
      acc[k] = __builtin_elementwise_fma(r, kv, acc[k]);
    }
  }

  if (w >= 4){
    #pragma unroll
    for (int k=0;k<16;k++)
      *(f32x4*)&par[w-4][k][l4*4] = acc[k];
  }
  __syncthreads();
  if (w < 4){
    #pragma unroll
    for (int k=0;k<16;k++){
      f32x4 tmp = *(const f32x4*)&par[w][k][l4*4];
      *(f32x4*)&par[w][k][l4*4] = tmp + acc[k];
    }
  }
  __syncthreads();
  int k = (w<<1) | (lane>>5);
  int j0 = lane & 31;
  float se_r = 0.0f;
  float* cp = corr + (size_t)b*NK*NHW + (size_t)k*NHW + px0;
  for (int jj=j0; jj<54; jj+=32){
    f32x4 s = *(const f32x4*)&par[0][k][jj*4];
    s += *(const f32x4*)&par[1][k][jj*4];
    s += *(const f32x4*)&par[2][k][jj*4];
    s += *(const f32x4*)&par[3][k][jj*4];
    *(f32x4*)(cp + jj*4) = s;
    se_r += (s.x+s.y) + (s.z+s.w);
  }
  #pragma unroll
  for (int off=16; off>0; off>>=1) se_r += __shfl_down(se_r, off, 32);
  if (j0 == 0)
    partial_se[(size_t)blk*16 + k] = se_r;
}

// ---- K3: SE gate + bf16 hi/lo theta/phi + V^T; 256-thread blocks --------
__global__ __launch_bounds__(256) void k_tpg(const float* __restrict__ corr,
    const float* __restrict__ partial_se,
    const float* __restrict__ w1, const float* __restrict__ w2,
    const float* __restrict__ tw, const float* __restrict__ tb,
    const float* __restrict__ pw, const float* __restrict__ pb,
    const float* __restrict__ gw, const float* __restrict__ gb,
    float* __restrict__ sscale,
    unsigned short* __restrict__ thetaX, unsigned short* __restrict__ phiX,
    unsigned short* __restrict__ gT){
  int blk = blockIdx.x;          // b*6 + ch
  int b = blk/6, ch = blk - b*6;
  int t = threadIdx.x;
  __shared__ float Wt[128], Wp[128], Wg[128], Bz[24], Ss[16], sS[16], sR[4];
  if (t < 128){ Wt[t]=tw[t]; Wp[t]=pw[t]; Wg[t]=gw[t]; }
  if (t < 8){ Bz[t]=tb[t]; Bz[8+t]=pb[t]; Bz[16+t]=gb[t]; }
  if (t >= 128 && t < 144){
    int q = t - 128;
    float a = 0.f;
    #pragma unroll
    for (int c2=0; c2<6; c2++) a += partial_se[(size_t)(b*6+c2)*16 + q];
    sS[q] = a * (1.0f/1296.0f);
  }
  __syncthreads();
  if (t < 4){
    float a=0.f;
    #pragma unroll
    for (int k=0;k<16;k++) a += sS[k]*w1[t*16+k];
    sR[t] = fmaxf(a, 0.f);
  }
  __syncthreads();
  if (t < 16){
    float a=0.f;
    #pragma unroll
    for (int j=0;j<4;j++) a += sR[j]*w2[t*4+j];
    float gsc = 1.0f/(1.0f+__expf(-a));
    Ss[t] = gsc;
    if (ch == 0) sscale[b*16+t] = gsc;
  }
  __syncthreads();
  int n = ch*256 + t;
  if (n >= NHW) return;
  float x[16];
  const float* cp = corr + (size_t)b*NK*NHW + n;
  #pragma unroll
  for (int c=0;c<16;c++) x[c] = cp[(size_t)c*NHW] * Ss[c];
  float th[8], ph[8], gg[8];
  #pragma unroll
  for (int o=0;o<8;o++){
    float a=Bz[o], p2=Bz[8+o], gq=Bz[16+o];
    #pragma unroll
    for (int c=0;c<16;c++){
      a  += Wt[o*16+c]*x[c];
      p2 += Wp[o*16+c]*x[c];
      gq += Wg[o*16+c]*x[c];
    }
    th[o]=a*LOG2E; ph[o]=p2; gg[o]=gq;   // theta pre-scaled: exp2 domain
  }
  unsigned short tH[8], tL[8], pH[8], pL[8];
  #pragma unroll
  for (int o=0;o<8;o++){
    unsigned short hh = bf16rn(th[o]);
    tH[o] = hh; tL[o] = bf16rn(th[o] - bf16tof(hh));
    unsigned short ph2 = bf16rn(ph[o]);
    pH[o] = ph2; pL[o] = bf16rn(ph[o] - bf16tof(ph2));
  }
  // row layout (16 ushorts): [H0-3 | L0-3 | H4-7 | L4-7]
  {
    u16x8* tp = (u16x8*)(thetaX + ((size_t)b*NPAD + n)*16);
    tp[0] = (u16x8){tH[0],tH[1],tH[2],tH[3], tL[0],tL[1],tL[2],tL[3]};
    tp[1] = (u16x8){tH[4],tH[5],tH[6],tH[7], tL[4],tL[5],tL[6],tL[7]};
    u16x8* pp = (u16x8*)(phiX + ((size_t)b*NPAD + n)*16);
    pp[0] = (u16x8){pH[0],pH[1],pH[2],pH[3], pL[0],pL[1],pL[2],pL[3]};
    pp[1] = (u16x8){pH[4],pH[5],pH[6],pH[7], pL[4],pL[5],pL[6],pL[7]};
  }
  #pragma unroll
  for (int o=0;o<8;o++)
    gT[((size_t)b*16 + o)*NPAD + n] = bf16rn(gg[o]);
  gT[((size_t)b*16 + 8)*NPAD + n] = 0x3F80;  // ones column -> l
}

// ---- K4a: partial online MFMA flash attention over one key-QUARTER ------
// r17 online math verbatim; r12 quarter indexing (kh in 0..3).
__global__ __launch_bounds__(128) void k_attn_part(
    const unsigned short* __restrict__ thetaX, const unsigned short* __restrict__ phiX,
    const unsigned short* __restrict__ gT,
    float* __restrict__ mpart, float* __restrict__ Ypart){
  int blk = blockIdx.x;
  int b = blk / 164, rem = blk - b*164;
  int qb = rem >> 2, kh = rem & 3;
  int t = threadIdx.x, w = t >> 6, lane = t & 63;
  int h = lane >> 5, r31 = lane & 31;
  __shared__ float smm[2][32];
  __shared__ float sY[5][64];
  __shared__ float yl[32][12];

  const unsigned short* thx = thetaX + (size_t)b*NPAD*16;
  const unsigned short* phx = phiX   + (size_t)b*NPAD*16;

  // B-frags (theta for query q=r31): lane h supplies k=h*4+j
  s16x4 Bh, Bl;
  {
    const s16x4* tp = (const s16x4*)(thx + ((size_t)(qb*32 + r31))*16 + h*8);
    Bh = tp[0]; Bl = tp[1];
  }

  // quarter boundaries {0,11,21,31,41}; 2-wave split inside the quarter
  int kbeg = (kh == 0) ? 0 : (kh*10 + 1);
  int kend = kh*10 + 11;
  int kmid = (kbeg + kend + 1) >> 1;
  int kt0 = w ? kmid : kbeg;
  int ktN = w ? kend : kmid;

  // ---- single pass: exact scores, online per-query rescale, swapped PV --
  float m = -1e30f;
  f32x16 Y = (f32x16)(0.0f);
  int colc = (r31 < 9) ? r31 : 0;        // A-operand row = V column (clamped)
  const unsigned short* gb2 = gT + ((size_t)b*16 + colc)*NPAD;

  {
    const unsigned short* prow = phx + (size_t)(kt0*32 + r31)*16 + h*8;
    const unsigned short* vrow = gb2 + kt0*32;
    for (int kt = kt0; kt < ktN; ++kt){
      const s16x4* pr = (const s16x4*)prow;
      s16x4 Ah = pr[0], Al = pr[1];
      f32x16 S = __builtin_amdgcn_mfma_f32_32x32x8bf16_1k(Ah, Bl, (f32x16)(0.0f), 0, 0, 0);
      S = __builtin_amdgcn_mfma_f32_32x32x8bf16_1k(Al, Bh, S, 0, 0, 0);
      S = __builtin_amdgcn_mfma_f32_32x32x8bf16_1k(Ah, Bh, S, 0, 0, 0);
      if (kt == 40){
        #pragma unroll
        for (int r=8;r<16;r++) S[r] = -1e30f;   // mask pad keys 1296..1311
      }
      // per-query tile max: tree over my 16 key-rows + pair combine
      float a0 = fmaxf(S[0],S[1]),  a1 = fmaxf(S[2],S[3]);
      float a2 = fmaxf(S[4],S[5]),  a3 = fmaxf(S[6],S[7]);
      float a4 = fmaxf(S[8],S[9]),  a5 = fmaxf(S[10],S[11]);
      float a6 = fmaxf(S[12],S[13]),a7 = fmaxf(S[14],S[15]);
      float b0 = fmaxf(a0,a1), b1 = fmaxf(a2,a3);
      float b2 = fmaxf(a4,a5), b3 = fmaxf(a6,a7);
      float tm = fmaxf(fmaxf(b0,b1), fmaxf(b2,b3));
      tm = fmaxf(tm, __shfl_xor(tm, 32));
      float mn = fmaxf(m, tm);
      float cf = __builtin_amdgcn_exp2f(m - mn);   // 0 on first tile
      m = mn;
      float p[16];
      #pragma unroll
      for (int r=0;r<16;r++) p[r] = __builtin_amdgcn_exp2f(S[r] - m);
      // rescale accumulator: lane = query, so per-lane cf is correct.
      // only rows 0..4 are consumed downstream.
      #pragma unroll
      for (int r=0;r<5;r++) Y[r] *= cf;
      unsigned int c[8];
      #pragma unroll
      for (int i=0;i<8;i++){
        unsigned int cc;
        asm("v_cvt_pk_bf16_f32 %0, %1, %2" : "=v"(cc) : "v"(p[2*i]), "v"(p[2*i+1]));
        c[i] = cc;
      }
      const s16x4* vr = (const s16x4*)(vrow + h*4);
      #pragma unroll
      for (int mf=0; mf<4; ++mf){
        s16x4 Ap = __builtin_bit_cast(s16x4, (u32x2){c[2*mf], c[2*mf+1]});
        s16x4 Vb = vr[mf*2];
        Y = __builtin_amdgcn_mfma_f32_32x32x8bf16_1k(Vb, Ap, Y, 0, 0, 0);  // SWAPPED
      }
      prow += 512;
      vrow += 32;
    }
  }

  // ---- cross-wave flash merge (per-query factors, lane = query) ---------
  if (h == 0) smm[w][r31] = m;
  __syncthreads();
  float M = fmaxf(smm[0][r31], smm[1][r31]);
  float cfw = __builtin_amdgcn_exp2f(m - M);
  #pragma unroll
  for (int r=0;r<5;r++) Y[r] *= cfw;
  if (w == 0 && h == 0)
    mpart[((size_t)((b*41 + qb)*4 + kh))*32 + r31] = M;
  if (w == 1){
    #pragma unroll
    for (int r=0;r<5;r++) sY[r][lane] = Y[r];
  }
  __syncthreads();
  if (w == 0){
    #pragma unroll
    for (int r=0;r<5;r++) Y[r] += sY[r][lane];
    // Y row v = (r&3)+8*(r>>2)+4h: h=0 -> v=r (r<4), v=8 (r=4); h=1 -> v=r+4
    if (h == 0){
      yl[r31][0]=Y[0]; yl[r31][1]=Y[1]; yl[r31][2]=Y[2]; yl[r31][3]=Y[3];
      yl[r31][8]=Y[4];
    } else {
      yl[r31][4]=Y[0]; yl[r31][5]=Y[1]; yl[r31][6]=Y[2]; yl[r31][7]=Y[3];
    }
  }
  __syncthreads();

  // ---- coalesced write-out of the 32x9 partial --------------------------
  float* yp = Ypart + (size_t)((b*41 + qb)*4 + kh)*288;
  for (int i = t; i < 288; i += 128){
    int q = i / 9, c2 = i - q*9;
    yp[i] = yl[q][c2];
  }
}

// ---- K4b: flash-merge four key-quarter partials + W-proj + residual -----
__global__ __launch_bounds__(128) void k_attn_fin(
    const float* __restrict__ mpart, const float* __restrict__ Ypart,
    const float* __restrict__ corr, const float* __restrict__ sscale,
    const float* __restrict__ Ww, const float* __restrict__ Wb,
    float* __restrict__ out){
  int blk = blockIdx.x;
  int b = blk / 41, qb = blk - b*41;
  int t = threadIdx.x;
  __shared__ float yl[32][9];
  __shared__ float cf[4][32];
  size_t p4 = (size_t)(b*41 + qb)*4;
  if (t < 32){
    float m0 = mpart[(p4+0)*32 + t];
    float m1 = mpart[(p4+1)*32 + t];
    float m2 = mpart[(p4+2)*32 + t];
    float m3 = mpart[(p4+3)*32 + t];
    float M = fmaxf(fmaxf(m0,m1), fmaxf(m2,m3));
    cf[0][t] = __builtin_amdgcn_exp2f(m0 - M);
    cf[1][t] = __builtin_amdgcn_exp2f(m1 - M);
    cf[2][t] = __builtin_amdgcn_exp2f(m2 - M);
    cf[3][t] = __builtin_amdgcn_exp2f(m3 - M);
  }
  __syncthreads();
  const float* y0 = Ypart + (p4+0)*288;
  const float* y1 = Ypart + (p4+1)*288;
  const float* y2 = Ypart + (p4+2)*288;
  const float* y3 = Ypart + (p4+3)*288;
  for (int i = t; i < 288; i += 128){
    int q = i / 9;
    ((float*)yl)[i] = (y0[i]*cf[0][q] + y1[i]*cf[1][q])
                    + (y2[i]*cf[2][q] + y3[i]*cf[3][q]);
  }
  __syncthreads();

  // epilogue: W-proj + residual; 128 threads = 32 q x 4 c-groups
  int q = t & 31, cg = t >> 5;
  int n = qb*32 + q;
  if (n < NHW){
    float il = 1.0f / yl[q][8];
    float yv[8];
    #pragma unroll
    for (int o=0;o<8;o++) yv[o] = yl[q][o] * il;
    const float* cp = corr + (size_t)b*NK*NHW + n;
    const float* ss = sscale + b*16;
    float* op = out + (size_t)b*NK*NHW + n;
    #pragma unroll
    for (int i=0;i<4;i++){
      int c2 = cg*4 + i;
      float z = Wb[c2];
      #pragma unroll
      for (int o=0;o<8;o++) z += Ww[c2*8+o]*yv[o];
      op[(size_t)c2*NHW] = z + cp[(size_t)c2*NHW]*ss[c2];
    }
  }
}

extern "C" void kernel_launch(void* const* d_in, const int* in_sizes, int n_in,
                              void* d_out, int out_size, void* d_ws, size_t ws_size,
                              hipStream_t stream){
  const float* feat1 = (const float*)d_in[0];
  const float* feat2 = (const float*)d_in[1];
  const float* bb1   = (const float*)d_in[2];
  const float* se_w1 = (const float*)d_in[3];
  const float* se_w2 = (const float*)d_in[4];
  const float* tw    = (const float*)d_in[5];
  const float* tb    = (const float*)d_in[6];
  const float* pw    = (const float*)d_in[7];
  const float* pb    = (const float*)d_in[8];
  const float* gw    = (const float*)d_in[9];
  const float* gb    = (const float*)d_in[10];
  const float* Ww    = (const float*)d_in[11];
  const float* Wb    = (const float*)d_in[12];
  float* out = (float*)d_out;

  float* ws = (float*)d_ws;
  float* kflat      = ws;                                // 64*256*16
  float* corr       = kflat + 64*256*16;                 // 64*16*1296
  float* partial_se = corr + (size_t)64*16*1296;         // 64*6*16
  float* sscale     = partial_se + 64*6*16;              // 64*16
  unsigned short* thetaX = (unsigned short*)(sscale + 64*16);   // 64*1312*16 u16
  unsigned short* phiX   = thetaX + (size_t)64*NPAD*16;         // 64*1312*16 u16
  unsigned short* gT     = phiX   + (size_t)64*NPAD*16;         // 64*16*1312 u16
  float* mpart = (float*)(gT + (size_t)64*16*NPAD);             // 64*41*4*32 f32
  float* Ypart = mpart + (size_t)64*41*4*32;                    // 64*41*4*288 f32

  hipLaunchKernelGGL(k_prpool, dim3(64*64), dim3(256), 0, stream, feat1, bb1, kflat);
  hipLaunchKernelGGL(k_corr, dim3(64*6), dim3(512), 0, stream, feat2, kflat, corr, partial_se);
  hipLaunchKernelGGL(k_tpg, dim3(64*6), dim3(256), 0, stream, corr, partial_se,
                     se_w1, se_w2, tw, tb, pw, pb, gw, gb, sscale, thetaX, phiX, gT);
  hipLaunchKernelGGL(k_attn_part, dim3(64*164), dim3(128), 0, stream,
                     thetaX, phiX, gT, mpart, Ypart);
  hipLaunchKernelGGL(k_attn_fin, dim3(64*41), dim3(128), 0, stream,
                     mpart, Ypart, corr, sscale, Ww, Wb, out);
}

// Round 20
// 101.082 us; speedup vs baseline: 1.0338x; 1.0338x over previous
//
#include <hip/hip_runtime.h>
#include <cmath>

#define NB 64
#define NCC 256
#define NH 36
#define NW 36
#define NHW 1296
#define NK 16
#define NI 8
#define SC (1.0f/16.0f)
#define LOG2E 1.4426950408889634f
#define NPAD 1312   // 41*32

typedef __attribute__((ext_vector_type(16))) float f32x16;
typedef __attribute__((ext_vector_type(4)))  float f32x4;
typedef __attribute__((ext_vector_type(4)))  short s16x4;
typedef __attribute__((ext_vector_type(8)))  unsigned short u16x8;
typedef __attribute__((ext_vector_type(2)))  unsigned int u32x2;

__device__ __forceinline__ float hatc(float t){
  t = fminf(fmaxf(t, -1.0f), 1.0f);
  float a = 1.0f + t, bq = 1.0f - t;
  return (t < 0.0f) ? 0.5f*a*a : 1.0f - 0.5f*bq*bq;
}

__device__ __forceinline__ unsigned short bf16rn(float f){
  unsigned int u = __builtin_bit_cast(unsigned int, f);
  return (unsigned short)((u + 0x7FFFu + ((u >> 16) & 1u)) >> 16);
}
__device__ __forceinline__ float bf16tof(unsigned short h){
  unsigned int u = ((unsigned int)h) << 16;
  return __builtin_bit_cast(float, u);
}

// ---- K1: PrRoI pooling; 1 wave per (b,c); float4 feature loads ----------
__global__ __launch_bounds__(256) void k_prpool(const float* __restrict__ feat1,
    const float* __restrict__ bb1, float* __restrict__ kflat){
  int blk = blockIdx.x;          // b*64 + cg
  int b = blk >> 6, cg = blk & 63;
  int t = threadIdx.x, w = t >> 6, lane = t & 63;
  int c = cg*4 + w;
  __shared__ float4 wY4[36];
  __shared__ float  wXp[36*5];
  float bx = bb1[b*4+0], by = bb1[b*4+1], bwv = bb1[b*4+2], bhv = bb1[b*4+3];
  float x1 = bx*SC, y1 = by*SC;
  float binw = bwv*SC*0.25f, binh = bhv*SC*0.25f;
  if (t < 36){
    float fi = (float)t;
    float4 r;
    r.x = hatc(y1 + 1.0f*binh - fi) - hatc(y1 + 0.0f*binh - fi);
    r.y = hatc(y1 + 2.0f*binh - fi) - hatc(y1 + 1.0f*binh - fi);
    r.z = hatc(y1 + 3.0f*binh - fi) - hatc(y1 + 2.0f*binh - fi);
    r.w = hatc(y1 + 4.0f*binh - fi) - hatc(y1 + 3.0f*binh - fi);
    wY4[t] = r;
  } else if (t < 72){
    int i = t - 36;
    float fi = (float)i;
    wXp[i*5+0] = hatc(x1 + 1.0f*binw - fi) - hatc(x1 + 0.0f*binw - fi);
    wXp[i*5+1] = hatc(x1 + 2.0f*binw - fi) - hatc(x1 + 1.0f*binw - fi);
    wXp[i*5+2] = hatc(x1 + 3.0f*binw - fi) - hatc(x1 + 2.0f*binw - fi);
    wXp[i*5+3] = hatc(x1 + 4.0f*binw - fi) - hatc(x1 + 3.0f*binw - fi);
  }
  __syncthreads();
  f32x4 acc4[4];
  #pragma unroll
  for (int p=0;p<4;p++) acc4[p] = (f32x4){0,0,0,0};
  const float4* fp4 = (const float4*)(feat1 + ((size_t)(b*256+c))*NHW);

  auto body = [&](float4 v, int px){
    #pragma unroll
    for (int j=0;j<4;j++){
      int p = px + j;
      int h = p/36, x = p - h*36;
      float vj = (j==0)?v.x:(j==1)?v.y:(j==2)?v.z:v.w;
      float4 wy = wY4[h];
      f32x4 wxv = {wXp[x*5+0], wXp[x*5+1], wXp[x*5+2], wXp[x*5+3]};
      f32x4 a0 = {vj*wy.x, vj*wy.x, vj*wy.x, vj*wy.x};
      f32x4 a1 = {vj*wy.y, vj*wy.y, vj*wy.y, vj*wy.y};
      f32x4 a2 = {vj*wy.z, vj*wy.z, vj*wy.z, vj*wy.z};
      f32x4 a3 = {vj*wy.w, vj*wy.w, vj*wy.w, vj*wy.w};
      acc4[0] = __builtin_elementwise_fma(a0, wxv, acc4[0]);
      acc4[1] = __builtin_elementwise_fma(a1, wxv, acc4[1]);
      acc4[2] = __builtin_elementwise_fma(a2, wxv, acc4[2]);
      acc4[3] = __builtin_elementwise_fma(a3, wxv, acc4[3]);
    }
  };

  #pragma unroll
  for (int i=0;i<5;i++){
    int f4i = i*64 + lane;
    float4 v = fp4[f4i];
    body(v, f4i*4);
  }
  if (lane < 4){
    int f4i = 320 + lane;
    float4 v = fp4[f4i];
    body(v, f4i*4);
  }
  float accf[16];
  #pragma unroll
  for (int p=0;p<4;p++){
    accf[p*4+0]=acc4[p].x; accf[p*4+1]=acc4[p].y;
    accf[p*4+2]=acc4[p].z; accf[p*4+3]=acc4[p].w;
  }
  #pragma unroll
  for (int k=0;k<16;k++){
    float a = accf[k];
    #pragma unroll
    for (int off=32; off>0; off>>=1) a += __shfl_down(a, off);
    accf[k] = a;
  }
  if (lane == 0){
    float area = binw*binh;
    float ia = (area > 0.0f) ? 1.0f/fmaxf(area,1e-12f) : 0.0f;
    float4* kp = (float4*)(kflat + ((size_t)(b*256+c))*16);
    kp[0] = make_float4(accf[0]*ia, accf[1]*ia, accf[2]*ia, accf[3]*ia);
    kp[1] = make_float4(accf[4]*ia, accf[5]*ia, accf[6]*ia, accf[7]*ia);
    kp[2] = make_float4(accf[8]*ia, accf[9]*ia, accf[10]*ia, accf[11]*ia);
    kp[3] = make_float4(accf[12]*ia, accf[13]*ia, accf[14]*ia, accf[15]*ia);
  }
}

// ---- K2: pixel corr; float4 pixel loads, 8-way channel split ------------
__global__ __launch_bounds__(512) void k_corr(const float* __restrict__ feat2,
    const float* __restrict__ kflat, float* __restrict__ corr,
    float* __restrict__ partial_se){
  int blk = blockIdx.x;          // b*6 + ch
  int b = blk / 6, ch = blk - b*6;
  int t = threadIdx.x, w = t >> 6, lane = t & 63;
  int px0 = ch*216;
  __shared__ float par[4][16][216];

  int wu = __builtin_amdgcn_readfirstlane(w);
  int c0 = wu*32;
  int l4 = (lane < 54) ? lane : 53;

  f32x4 acc[16];
  #pragma unroll
  for (int k=0;k<16;k++) acc[k] = (f32x4){0,0,0,0};

  const float* f2base = feat2 + (size_t)b*NCC*NHW + px0 + l4*4;
  const float* kfb = kflat + (size_t)b*4096;
  #pragma unroll 4
  for (int c = c0; c < c0+32; ++c){
    f32x4 r = *(const f32x4*)(f2base + (size_t)c*NHW);
    f32x16 kf = *(const f32x16*)(kfb + c*16);
    #pragma unroll
    for (int k=0;k<16;k++){
      f32x4 kv = {kf[k], kf[k], kf[k], kf[k]};
      acc[k] = __builtin_elementwise_fma(r, kv, acc[k]);
    }
  }

  if (w >= 4){
    #pragma unroll
    for (int k=0;k<16;k++)
      *(f32x4*)&par[w-4][k][l4*4] = acc[k];
  }
  __syncthreads();
  if (w < 4){
    #pragma unroll
    for (int k=0;k<16;k++){
      f32x4 tmp = *(const f32x4*)&par[w][k][l4*4];
      *(f32x4*)&par[w][k][l4*4] = tmp + acc[k];
    }
  }
  __syncthreads();
  int k = (w<<1) | (lane>>5);
  int j0 = lane & 31;
  float se_r = 0.0f;
  float* cp = corr + (size_t)b*NK*NHW + (size_t)k*NHW + px0;
  for (int jj=j0; jj<54; jj+=32){
    f32x4 s = *(const f32x4*)&par[0][k][jj*4];
    s += *(const f32x4*)&par[1][k][jj*4];
    s += *(const f32x4*)&par[2][k][jj*4];
    s += *(const f32x4*)&par[3][k][jj*4];
    *(f32x4*)(cp + jj*4) = s;
    se_r += (s.x+s.y) + (s.z+s.w);
  }
  #pragma unroll
  for (int off=16; off>0; off>>=1) se_r += __shfl_down(se_r, off, 32);
  if (j0 == 0)
    partial_se[(size_t)blk*16 + k] = se_r;
}

// ---- K3: SE gate + bf16 hi/lo theta/phi + V^T; 256-thread blocks --------
__global__ __launch_bounds__(256) void k_tpg(const float* __restrict__ corr,
    const float* __restrict__ partial_se,
    const float* __restrict__ w1, const float* __restrict__ w2,
    const float* __restrict__ tw, const float* __restrict__ tb,
    const float* __restrict__ pw, const float* __restrict__ pb,
    const float* __restrict__ gw, const float* __restrict__ gb,
    float* __restrict__ sscale,
    unsigned short* __restrict__ thetaX, unsigned short* __restrict__ phiX,
    unsigned short* __restrict__ gT){
  int blk = blockIdx.x;          // b*6 + ch
  int b = blk/6, ch = blk - b*6;
  int t = threadIdx.x;
  __shared__ float Wt[128], Wp[128], Wg[128], Bz[24], Ss[16], sS[16], sR[4];
  if (t < 128){ Wt[t]=tw[t]; Wp[t]=pw[t]; Wg[t]=gw[t]; }
  if (t < 8){ Bz[t]=tb[t]; Bz[8+t]=pb[t]; Bz[16+t]=gb[t]; }
  if (t >= 128 && t < 144){
    int q = t - 128;
    float a = 0.f;
    #pragma unroll
    for (int c2=0; c2<6; c2++) a += partial_se[(size_t)(b*6+c2)*16 + q];
    sS[q] = a * (1.0f/1296.0f);
  }
  __syncthreads();
  if (t < 4){
    float a=0.f;
    #pragma unroll
    for (int k=0;k<16;k++) a += sS[k]*w1[t*16+k];
    sR[t] = fmaxf(a, 0.f);
  }
  __syncthreads();
  if (t < 16){
    float a=0.f;
    #pragma unroll
    for (int j=0;j<4;j++) a += sR[j]*w2[t*4+j];
    float gsc = 1.0f/(1.0f+__expf(-a));
    Ss[t] = gsc;
    if (ch == 0) sscale[b*16+t] = gsc;
  }
  __syncthreads();
  int n = ch*256 + t;
  if (n >= NHW) return;
  float x[16];
  const float* cp = corr + (size_t)b*NK*NHW + n;
  #pragma unroll
  for (int c=0;c<16;c++) x[c] = cp[(size_t)c*NHW] * Ss[c];
  float th[8], ph[8], gg[8];
  #pragma unroll
  for (int o=0;o<8;o++){
    float a=Bz[o], p2=Bz[8+o], gq=Bz[16+o];
    #pragma unroll
    for (int c=0;c<16;c++){
      a  += Wt[o*16+c]*x[c];
      p2 += Wp[o*16+c]*x[c];
      gq += Wg[o*16+c]*x[c];
    }
    th[o]=a*LOG2E; ph[o]=p2; gg[o]=gq;   // theta pre-scaled: exp2 domain
  }
  unsigned short tH[8], tL[8], pH[8], pL[8];
  #pragma unroll
  for (int o=0;o<8;o++){
    unsigned short hh = bf16rn(th[o]);
    tH[o] = hh; tL[o] = bf16rn(th[o] - bf16tof(hh));
    unsigned short ph2 = bf16rn(ph[o]);
    pH[o] = ph2; pL[o] = bf16rn(ph[o] - bf16tof(ph2));
  }
  // row layout (16 ushorts): [H0-3 | L0-3 | H4-7 | L4-7]
  {
    u16x8* tp = (u16x8*)(thetaX + ((size_t)b*NPAD + n)*16);
    tp[0] = (u16x8){tH[0],tH[1],tH[2],tH[3], tL[0],tL[1],tL[2],tL[3]};
    tp[1] = (u16x8){tH[4],tH[5],tH[6],tH[7], tL[4],tL[5],tL[6],tL[7]};
    u16x8* pp = (u16x8*)(phiX + ((size_t)b*NPAD + n)*16);
    pp[0] = (u16x8){pH[0],pH[1],pH[2],pH[3], pL[0],pL[1],pL[2],pL[3]};
    pp[1] = (u16x8){pH[4],pH[5],pH[6],pH[7], pL[4],pL[5],pL[6],pL[7]};
  }
  #pragma unroll
  for (int o=0;o<8;o++)
    gT[((size_t)b*16 + o)*NPAD + n] = bf16rn(gg[o]);
  gT[((size_t)b*16 + 8)*NPAD + n] = 0x3F80;  // ones column -> l
}

// ---- K4a: partial MFMA flash attention, ONLINE single pass --------------
// PV operands SWAPPED: Y = mfma(Vb, Ap, Y) -> Y[row=Vcol][col=query], so
// per-lane (=query) online rescale is valid. Same fragments as verified r6.
__global__ __launch_bounds__(128) void k_attn_part(
    const unsigned short* __restrict__ thetaX, const unsigned short* __restrict__ phiX,
    const unsigned short* __restrict__ gT,
    float* __restrict__ mpart, float* __restrict__ Ypart){
  int blk = blockIdx.x;
  int b = blk / 82, rem = blk - b*82;
  int qb = rem >> 1, kh = rem & 1;
  int t = threadIdx.x, w = t >> 6, lane = t & 63;
  int h = lane >> 5, r31 = lane & 31;
  __shared__ float smm[2][32];
  __shared__ float sY[5][64];
  __shared__ float yl[32][12];

  const unsigned short* thx = thetaX + (size_t)b*NPAD*16;
  const unsigned short* phx = phiX   + (size_t)b*NPAD*16;

  // B-frags (theta for query q=r31): lane h supplies k=h*4+j
  s16x4 Bh, Bl;
  {
    const s16x4* tp = (const s16x4*)(thx + ((size_t)(qb*32 + r31))*16 + h*8);
    Bh = tp[0]; Bl = tp[1];
  }

  int kbeg = kh ? 21 : 0;
  int kend = kh ? 41 : 21;
  int kmid = kh ? 31 : 11;
  int kt0 = w ? kmid : kbeg;
  int ktN = w ? kend : kmid;

  // ---- single pass: exact scores, online per-query rescale, swapped PV --
  float m = -1e30f;
  f32x16 Y = (f32x16)(0.0f);
  int colc = (r31 < 9) ? r31 : 0;        // A-operand row = V column (clamped)
  const unsigned short* gb2 = gT + ((size_t)b*16 + colc)*NPAD;

  {
    const unsigned short* prow = phx + (size_t)(kt0*32 + r31)*16 + h*8;
    const unsigned short* vrow = gb2 + kt0*32;
    for (int kt = kt0; kt < ktN; ++kt){
      const s16x4* pr = (const s16x4*)prow;
      s16x4 Ah = pr[0], Al = pr[1];
      f32x16 S = __builtin_amdgcn_mfma_f32_32x32x8bf16_1k(Ah, Bl, (f32x16)(0.0f), 0, 0, 0);
      S = __builtin_amdgcn_mfma_f32_32x32x8bf16_1k(Al, Bh, S, 0, 0, 0);
      S = __builtin_amdgcn_mfma_f32_32x32x8bf16_1k(Ah, Bh, S, 0, 0, 0);
      if (kt == 40){
        #pragma unroll
        for (int r=8;r<16;r++) S[r] = -1e30f;   // mask pad keys 1296..1311
      }
      // per-query tile max: tree over my 16 key-rows + pair combine
      float a0 = fmaxf(S[0],S[1]),  a1 = fmaxf(S[2],S[3]);
      float a2 = fmaxf(S[4],S[5]),  a3 = fmaxf(S[6],S[7]);
      float a4 = fmaxf(S[8],S[9]),  a5 = fmaxf(S[10],S[11]);
      float a6 = fmaxf(S[12],S[13]),a7 = fmaxf(S[14],S[15]);
      float b0 = fmaxf(a0,a1), b1 = fmaxf(a2,a3);
      float b2 = fmaxf(a4,a5), b3 = fmaxf(a6,a7);
      float tm = fmaxf(fmaxf(b0,b1), fmaxf(b2,b3));
      tm = fmaxf(tm, __shfl_xor(tm, 32));
      float mn = fmaxf(m, tm);
      float cf = __builtin_amdgcn_exp2f(m - mn);   // 0 on first tile
      m = mn;
      float p[16];
      #pragma unroll
      for (int r=0;r<16;r++) p[r] = __builtin_amdgcn_exp2f(S[r] - m);
      // rescale accumulator: lane = query, so per-lane cf is correct.
      // only rows 0..4 are consumed downstream.
      #pragma unroll
      for (int r=0;r<5;r++) Y[r] *= cf;
      unsigned int c[8];
      #pragma unroll
      for (int i=0;i<8;i++){
        unsigned int cc;
        asm("v_cvt_pk_bf16_f32 %0, %1, %2" : "=v"(cc) : "v"(p[2*i]), "v"(p[2*i+1]));
        c[i] = cc;
      }
      const s16x4* vr = (const s16x4*)(vrow + h*4);
      #pragma unroll
      for (int mf=0; mf<4; ++mf){
        s16x4 Ap = __builtin_bit_cast(s16x4, (u32x2){c[2*mf], c[2*mf+1]});
        s16x4 Vb = vr[mf*2];
        Y = __builtin_amdgcn_mfma_f32_32x32x8bf16_1k(Vb, Ap, Y, 0, 0, 0);  // SWAPPED
      }
      prow += 512;
      vrow += 32;
    }
  }

  // ---- cross-wave flash merge (per-query factors, lane = query) ---------
  if (h == 0) smm[w][r31] = m;
  __syncthreads();
  float M = fmaxf(smm[0][r31], smm[1][r31]);
  float cfw = __builtin_amdgcn_exp2f(m - M);
  #pragma unroll
  for (int r=0;r<5;r++) Y[r] *= cfw;
  if (w == 0 && h == 0)
    mpart[((size_t)((b*41 + qb)*2 + kh))*32 + r31] = M;
  if (w == 1){
    #pragma unroll
    for (int r=0;r<5;r++) sY[r][lane] = Y[r];
  }
  __syncthreads();
  if (w == 0){
    #pragma unroll
    for (int r=0;r<5;r++) Y[r] += sY[r][lane];
    // Y row v = (r&3)+8*(r>>2)+4h: h=0 -> v=r (r<4), v=8 (r=4); h=1 -> v=r+4
    if (h == 0){
      yl[r31][0]=Y[0]; yl[r31][1]=Y[1]; yl[r31][2]=Y[2]; yl[r31][3]=Y[3];
      yl[r31][8]=Y[4];
    } else {
      yl[r31][4]=Y[0]; yl[r31][5]=Y[1]; yl[r31][6]=Y[2]; yl[r31][7]=Y[3];
    }
  }
  __syncthreads();

  // ---- coalesced write-out of the 32x9 partial --------------------------
  float* yp = Ypart + (size_t)((b*41 + qb)*2 + kh)*288;
  for (int i = t; i < 288; i += 128){
    int q = i / 9, c2 = i - q*9;
    yp[i] = yl[q][c2];
  }
}

// ---- K4b: flash-merge two key-half partials + W-proj + residual ---------
__global__ __launch_bounds__(128) void k_attn_fin(
    const float* __restrict__ mpart, const float* __restrict__ Ypart,
    const float* __restrict__ corr, const float* __restrict__ sscale,
    const float* __restrict__ Ww, const float* __restrict__ Wb,
    float* __restrict__ out){
  int blk = blockIdx.x;
  int b = blk / 41, qb = blk - b*41;
  int t = threadIdx.x;
  __shared__ float yl[32][9];
  __shared__ float cf0[32], cf1[32];
  size_t p2 = (size_t)(b*41 + qb)*2;
  if (t < 32){
    float m0 = mpart[p2*32 + t];
    float m1 = mpart[(p2+1)*32 + t];
    float M = fmaxf(m0, m1);
    cf0[t] = __builtin_amdgcn_exp2f(m0 - M);
    cf1[t] = __builtin_amdgcn_exp2f(m1 - M);
  }
  __syncthreads();
  const float* y0 = Ypart + p2*288;
  const float* y1 = Ypart + (p2+1)*288;
  for (int i = t; i < 288; i += 128){
    int q = i / 9;
    ((float*)yl)[i] = y0[i]*cf0[q] + y1[i]*cf1[q];
  }
  __syncthreads();

  // epilogue: W-proj + residual; 128 threads = 32 q x 4 c-groups
  int q = t & 31, cg = t >> 5;
  int n = qb*32 + q;
  if (n < NHW){
    float il = 1.0f / yl[q][8];
    float yv[8];
    #pragma unroll
    for (int o=0;o<8;o++) yv[o] = yl[q][o] * il;
    const float* cp = corr + (size_t)b*NK*NHW + n;
    const float* ss = sscale + b*16;
    float* op = out + (size_t)b*NK*NHW + n;
    #pragma unroll
    for (int i=0;i<4;i++){
      int c2 = cg*4 + i;
      float z = Wb[c2];
      #pragma unroll
      for (int o=0;o<8;o++) z += Ww[c2*8+o]*yv[o];
      op[(size_t)c2*NHW] = z + cp[(size_t)c2*NHW]*ss[c2];
    }
  }
}

extern "C" void kernel_launch(void* const* d_in, const int* in_sizes, int n_in,
                              void* d_out, int out_size, void* d_ws, size_t ws_size,
                              hipStream_t stream){
  const float* feat1 = (const float*)d_in[0];
  const float* feat2 = (const float*)d_in[1];
  const float* bb1   = (const float*)d_in[2];
  const float* se_w1 = (const float*)d_in[3];
  const float* se_w2 = (const float*)d_in[4];
  const float* tw    = (const float*)d_in[5];
  const float* tb    = (const float*)d_in[6];
  const float* pw    = (const float*)d_in[7];
  const float* pb    = (const float*)d_in[8];
  const float* gw    = (const float*)d_in[9];
  const float* gb    = (const float*)d_in[10];
  const float* Ww    = (const float*)d_in[11];
  const float* Wb    = (const float*)d_in[12];
  float* out = (float*)d_out;

  float* ws = (float*)d_ws;
  float* kflat      = ws;                                // 64*256*16
  float* corr       = kflat + 64*256*16;                 // 64*16*1296
  float* partial_se = corr + (size_t)64*16*1296;         // 64*6*16
  float* sscale     = partial_se + 64*6*16;              // 64*16
  unsigned short* thetaX = (unsigned short*)(sscale + 64*16);   // 64*1312*16 u16
  unsigned short* phiX   = thetaX + (size_t)64*NPAD*16;         // 64*1312*16 u16
  unsigned short* gT     = phiX   + (size_t)64*NPAD*16;         // 64*16*1312 u16
  float* mpart = (float*)(gT + (size_t)64*16*NPAD);             // 64*41*2*32 f32
  float* Ypart = mpart + (size_t)64*41*2*32;                    // 64*41*2*288 f32

  hipLaunchKernelGGL(k_prpool, dim3(64*64), dim3(256), 0, stream, feat1, bb1, kflat);
  hipLaunchKernelGGL(k_corr, dim3(64*6), dim3(512), 0, stream, feat2, kflat, corr, partial_se);
  hipLaunchKernelGGL(k_tpg, dim3(64*6), dim3(256), 0, stream, corr, partial_se,
                     se_w1, se_w2, tw, tb, pw, pb, gw, gb, sscale, thetaX, phiX, gT);
  hipLaunchKernelGGL(k_attn_part, dim3(64*82), dim3(128), 0, stream,
                     thetaX, phiX, gT, mpart, Ypart);
  hipLaunchKernelGGL(k_attn_fin, dim3(64*41), dim3(128), 0, stream,
                     mpart, Ypart, corr, sscale, Ww, Wb, out);
}